// Round 2
// baseline (5558.288 us; speedup 1.0000x reference)
//
#include <hip/hip_runtime.h>
#include <cstdint>
#include <cstddef>

// Problem constants (from reference)
constexpr int HID  = 3072;   // hidden size (K of GEMM1, N of GEMM2)
constexpr int ITR  = 8192;   // intermediate size
constexpr int MTOK = 8192;   // B*S = 4*2048 tokens

typedef int i32x4 __attribute__((ext_vector_type(4)));

// ---------- helpers ----------

// RNE fp32 -> bf16 bits
__device__ inline unsigned short f2bf(float f) {
  unsigned int u = __float_as_uint(f);
  u = (u + 0x7FFFu + ((u >> 16) & 1u)) >> 16;
  return (unsigned short)u;
}

// async global->LDS, 16B per lane. LDS dest is wave-uniform base; HW writes
// dest + lane*16.
__device__ inline void gl2lds16(const void* g, void* l) {
  __builtin_amdgcn_global_load_lds(
      (const __attribute__((address_space(1))) unsigned int*)(uintptr_t)g,
      (__attribute__((address_space(3))) unsigned int*)(unsigned int)(uintptr_t)l,
      16, 0, 0);
}

// ---------- prep kernels (unchanged) ----------

__global__ __launch_bounds__(256) void quant_x(
    const float* __restrict__ x, signed char* __restrict__ xq,
    float* __restrict__ qs) {
  const int row = blockIdx.x;
  const int t = threadIdx.x;
  const int wave = t >> 6, lane = t & 63;
  const float4* xr = (const float4*)(x + (size_t)row * HID);  // 768 float4
  float4 v[3];
  float m = 0.f;
#pragma unroll
  for (int k = 0; k < 3; k++) {
    v[k] = xr[t + 256 * k];
    m = fmaxf(m, fmaxf(fmaxf(fabsf(v[k].x), fabsf(v[k].y)),
                       fmaxf(fabsf(v[k].z), fabsf(v[k].w))));
  }
#pragma unroll
  for (int off = 32; off >= 1; off >>= 1) m = fmaxf(m, __shfl_down(m, off));
  __shared__ float wm[4];
  if (lane == 0) wm[wave] = m;
  __syncthreads();
  const float am = fmaxf(fmaxf(wm[0], wm[1]), fmaxf(wm[2], wm[3]));
  const float inv = (am > 1e-30f) ? 127.f / am : 0.f;
  if (t == 0) qs[row] = (am > 1e-30f) ? am / 127.f : 1.f;
  int* out = (int*)(xq + (size_t)row * HID);
#pragma unroll
  for (int k = 0; k < 3; k++) {
    int r0 = __float2int_rn(v[k].x * inv);
    int r1 = __float2int_rn(v[k].y * inv);
    int r2 = __float2int_rn(v[k].z * inv);
    int r3 = __float2int_rn(v[k].w * inv);
    out[t + 256 * k] =
        (r0 & 255) | ((r1 & 255) << 8) | ((r2 & 255) << 16) | ((r3 & 255) << 24);
  }
}

// w1 int32 -> int8 with gate/up 16-row interleave
__global__ __launch_bounds__(256) void cvt_w1_i8(
    const int* __restrict__ in, signed char* __restrict__ out) {
  const int nw = 2 * ITR * (HID / 4);
  int i = blockIdx.x * 256 + threadIdx.x;
  if (i >= nw) return;
  const int R  = i / (HID / 4);
  const int c4 = i % (HID / 4);
  const int q = R >> 5, rm = R & 31;
  const int orig = (rm < 16) ? (q * 16 + rm) : (ITR + q * 16 + (rm - 16));
  int4 w = ((const int4*)(in + (size_t)orig * HID))[c4];
  ((int*)out)[(size_t)R * (HID / 4) + c4] =
      (w.x & 255) | ((w.y & 255) << 8) | ((w.z & 255) << 16) | ((w.w & 255) << 24);
}

// w2 int32 -> int8, layout preserved ([HID, ITR], k contiguous)
__global__ __launch_bounds__(256) void cvt_w2_i8(
    const int* __restrict__ in, signed char* __restrict__ out) {
  const int nw = HID * (ITR / 4);
  int i = blockIdx.x * 256 + threadIdx.x;
  if (i >= nw) return;
  int4 w = ((const int4*)in)[i];
  ((int*)out)[i] =
      (w.x & 255) | ((w.y & 255) << 8) | ((w.z & 255) << 16) | ((w.w & 255) << 24);
}

// per-token int8 quantization of hidden (bf16 in)
__global__ __launch_bounds__(256) void quant_h(
    const unsigned short* __restrict__ h, signed char* __restrict__ hq,
    float* __restrict__ qh) {
  const int row = blockIdx.x;
  const int t = threadIdx.x;
  const int wave = t >> 6, lane = t & 63;
  const uint4* hr = (const uint4*)(h + (size_t)row * ITR);  // 1024 uint4
  uint4 v[4];
  float f[32];
  float m = 0.f;
#pragma unroll
  for (int k = 0; k < 4; k++) {
    v[k] = hr[t + 256 * k];
    const unsigned int w[4] = {v[k].x, v[k].y, v[k].z, v[k].w};
#pragma unroll
    for (int j = 0; j < 4; j++) {
      float lo = __uint_as_float(w[j] << 16);
      float hi = __uint_as_float(w[j] & 0xFFFF0000u);
      f[k * 8 + 2 * j]     = lo;
      f[k * 8 + 2 * j + 1] = hi;
      m = fmaxf(m, fmaxf(fabsf(lo), fabsf(hi)));
    }
  }
#pragma unroll
  for (int off = 32; off >= 1; off >>= 1) m = fmaxf(m, __shfl_down(m, off));
  __shared__ float wm[4];
  if (lane == 0) wm[wave] = m;
  __syncthreads();
  const float am = fmaxf(fmaxf(wm[0], wm[1]), fmaxf(wm[2], wm[3]));
  const float inv = (am > 1e-30f) ? 127.f / am : 0.f;
  if (t == 0) qh[row] = (am > 1e-30f) ? am / 127.f : 1.f;
  int* out = (int*)(hq + (size_t)row * ITR);
#pragma unroll
  for (int k = 0; k < 4; k++) {
#pragma unroll
    for (int j = 0; j < 2; j++) {
      int r0 = __float2int_rn(f[k * 8 + 4 * j]     * inv);
      int r1 = __float2int_rn(f[k * 8 + 4 * j + 1] * inv);
      int r2 = __float2int_rn(f[k * 8 + 4 * j + 2] * inv);
      int r3 = __float2int_rn(f[k * 8 + 4 * j + 3] * inv);
      out[(t + 256 * k) * 2 + j] =
          (r0 & 255) | ((r1 & 255) << 8) | ((r2 & 255) << 16) | ((r3 & 255) << 24);
    }
  }
}

// ---------- GEMM v3: co-residency over pipeline depth ------------------------
// gemm1: 256x256 tile, BK=64, 2-buffer LDS (64 KB) -> 2 blocks/CU.
// One phase + ONE barrier per K-tile:
//   stage(t+1) issue-early -> 12 frag ds_reads -> lgkmcnt(0) -> 32 MFMA
//   -> vmcnt(0) drain-late (~650cy after issue, nearly free) -> s_barrier.
// Cross-block overlap (m114) hides the drain; barriers drop 4/tile -> 1/tile.
// Numerics bit-identical to v2 (same MFMA order, exact i32 accumulation).

__global__ __launch_bounds__(512, 4) void gemm1_i8_v3(
    const signed char* __restrict__ A, const signed char* __restrict__ B,
    const float* __restrict__ qs, const float* __restrict__ scales,
    unsigned short* __restrict__ Hout) {
  constexpr int K = HID, NT = K / 64;     // 48 K-tiles
  constexpr int MB = MTOK / 256;          // 32
  constexpr int NB = (2 * ITR) / 256;     // 64
  constexpr int PN = 4;

  const int tid = threadIdx.x;
  const int wave = tid >> 6, lane = tid & 63;

  // XCD-bijective swizzle (2048 % 8 == 0) + PN-panel, mb-major inside panel
  const int bid = blockIdx.x;
  const int wg = (bid & 7) * (MB * NB / 8) + (bid >> 3);
  const int panel = wg / (PN * MB);
  const int rem = wg - panel * (PN * MB);
  const int nb = panel * PN + (rem & (PN - 1));
  const int mb = rem / PN;
  const int m0 = mb * 256;
  const int n0 = nb * 256;  // interleaved gate/up column space [0, 2*ITR)

  __shared__ __align__(16) signed char sA[2][256 * 64];  // 32 KB
  __shared__ __align__(16) signed char sB[2][256 * 64];  // 32 KB

  const int srow  = wave * 32 + (lane >> 2);
  const int chunk = (lane & 3) ^ ((lane >> 3) & 3);  // XOR-swizzled src chunk
  const signed char* Ag = A + (size_t)(m0 + srow) * K + chunk * 16;
  const signed char* Bg = B + (size_t)(n0 + srow) * K + chunk * 16;
  const int ldsw = (wave * 32) * 64;  // wave-uniform LDS staging base (bytes)

  auto stage = [&](int ks, int b) {
    gl2lds16(Ag + ks * 64,          &sA[b][ldsw]);
    gl2lds16(Ag + ks * 64 + 16 * K, &sA[b][ldsw + 1024]);
    gl2lds16(Bg + ks * 64,          &sB[b][ldsw]);
    gl2lds16(Bg + ks * 64 + 16 * K, &sB[b][ldsw + 1024]);
  };

  i32x4 acc[8][4];
#pragma unroll
  for (int i = 0; i < 8; i++)
#pragma unroll
    for (int j = 0; j < 4; j++) acc[i][j] = (i32x4){0, 0, 0, 0};

  const int wr = wave >> 2, wc = wave & 3;
  const int ml = lane & 15;
  const int q  = lane >> 4;
  const int slot = (q ^ ((ml >> 1) & 3)) * 16;  // swizzled read slot (bytes)

  stage(0, 0);
  asm volatile("s_waitcnt vmcnt(0)" ::: "memory");
  __builtin_amdgcn_s_barrier();

  int cur = 0;
  for (int t = 0; t < NT; ++t) {
    // issue next tile's staging first (max issue->drain distance)
    if (t + 1 < NT) stage(t + 1, cur ^ 1);
    const signed char* a_ = sA[cur];
    const signed char* b_ = sB[cur];
    i32x4 av[8], bv[4];
#pragma unroll
    for (int j = 0; j < 4; j++)
      bv[j] = *(const i32x4*)&b_[(wc * 64 + j * 16 + ml) * 64 + slot];
#pragma unroll
    for (int i = 0; i < 8; i++)
      av[i] = *(const i32x4*)&a_[(wr * 128 + i * 16 + ml) * 64 + slot];
    asm volatile("s_waitcnt lgkmcnt(0)" ::: "memory");
    __builtin_amdgcn_sched_barrier(0);
    __builtin_amdgcn_s_setprio(1);
#pragma unroll
    for (int i = 0; i < 8; i++)
#pragma unroll
      for (int j = 0; j < 4; j++)
        acc[i][j] = __builtin_amdgcn_mfma_i32_16x16x64_i8(av[i], bv[j], acc[i][j], 0, 0, 0);
    __builtin_amdgcn_s_setprio(0);
    asm volatile("s_waitcnt vmcnt(0)" ::: "memory");
    __builtin_amdgcn_s_barrier();
    cur ^= 1;
  }

  // Epilogue: j pairs (0,1),(2,3) = (gate,up) for the same 16 hidden cols.
  // C/D layout: col = lane&15, row = (lane>>4)*4 + reg
#pragma unroll
  for (int jp = 0; jp < 2; jp++) {
    const int hcol = (n0 + wc * 64) / 2 + jp * 16 + ml;
    const float sg = scales[hcol];
    const float su = scales[ITR + hcol];
#pragma unroll
    for (int i = 0; i < 8; i++) {
      const int mrow = m0 + wr * 128 + i * 16 + q * 4;
#pragma unroll
      for (int r = 0; r < 4; r++) {
        const float rowqs = qs[mrow + r];
        float g = (float)acc[i][2 * jp][r] * sg * rowqs;
        float u = (float)acc[i][2 * jp + 1][r] * su * rowqs;
        float h = (g / (1.f + __expf(-g))) * u;  // silu(g)*u
        Hout[(size_t)(mrow + r) * ITR + hcol] = f2bf(h);
      }
    }
  }
}

// gemm2: 256x128 tile, 2-buffer LDS (48 KB) -> 3 blocks/CU; grid 768 = exactly
// 3/CU x 256 (fixes 384-block imbalance). Waves 4M x 2N, per-wave 64x64.
__global__ __launch_bounds__(512, 6) void gemm2_i8_v3(
    const signed char* __restrict__ A, const signed char* __restrict__ B,
    const float* __restrict__ qh, const float* __restrict__ scales,
    float* __restrict__ Cout) {
  constexpr int K = ITR, N = HID, NT = K / 64;  // 128 K-tiles
  constexpr int MB = MTOK / 256;                // 32
  constexpr int NB = N / 128;                   // 24
  constexpr int PN = 2;

  const int tid = threadIdx.x;
  const int wave = tid >> 6, lane = tid & 63;

  const int bid = blockIdx.x;  // 768 blocks, 768 % 8 == 0
  const int wg = (bid & 7) * (MB * NB / 8) + (bid >> 3);
  const int panel = wg / (PN * MB);
  const int rem = wg - panel * (PN * MB);
  const int nb = panel * PN + (rem & (PN - 1));
  const int mb = rem / PN;
  const int m0 = mb * 256;
  const int n0 = nb * 128;

  __shared__ __align__(16) signed char sA[2][256 * 64];  // 32 KB
  __shared__ __align__(16) signed char sB[2][128 * 64];  // 16 KB

  const int srowA = wave * 32 + (lane >> 2);
  const int srowB = wave * 16 + (lane >> 2);
  const int chunk = (lane & 3) ^ ((lane >> 3) & 3);
  const signed char* Ag = A + (size_t)(m0 + srowA) * K + chunk * 16;
  const signed char* Bg = B + (size_t)(n0 + srowB) * K + chunk * 16;
  const int ldswA = (wave * 32) * 64;
  const int ldswB = (wave * 16) * 64;

  auto stage = [&](int ks, int b) {
    gl2lds16(Ag + ks * 64,          &sA[b][ldswA]);
    gl2lds16(Ag + ks * 64 + 16 * K, &sA[b][ldswA + 1024]);
    gl2lds16(Bg + ks * 64,          &sB[b][ldswB]);
  };

  i32x4 acc[4][4];
#pragma unroll
  for (int i = 0; i < 4; i++)
#pragma unroll
    for (int j = 0; j < 4; j++) acc[i][j] = (i32x4){0, 0, 0, 0};

  const int wr = wave >> 1, wc = wave & 1;  // 4M x 2N
  const int ml = lane & 15;
  const int q  = lane >> 4;
  const int slot = (q ^ ((ml >> 1) & 3)) * 16;

  stage(0, 0);
  asm volatile("s_waitcnt vmcnt(0)" ::: "memory");
  __builtin_amdgcn_s_barrier();

  int cur = 0;
  for (int t = 0; t < NT; ++t) {
    if (t + 1 < NT) stage(t + 1, cur ^ 1);
    const signed char* a_ = sA[cur];
    const signed char* b_ = sB[cur];
    i32x4 av[4], bv[4];
#pragma unroll
    for (int j = 0; j < 4; j++)
      bv[j] = *(const i32x4*)&b_[(wc * 64 + j * 16 + ml) * 64 + slot];
#pragma unroll
    for (int i = 0; i < 4; i++)
      av[i] = *(const i32x4*)&a_[(wr * 64 + i * 16 + ml) * 64 + slot];
    asm volatile("s_waitcnt lgkmcnt(0)" ::: "memory");
    __builtin_amdgcn_sched_barrier(0);
    __builtin_amdgcn_s_setprio(1);
#pragma unroll
    for (int i = 0; i < 4; i++)
#pragma unroll
      for (int j = 0; j < 4; j++)
        acc[i][j] = __builtin_amdgcn_mfma_i32_16x16x64_i8(av[i], bv[j], acc[i][j], 0, 0, 0);
    __builtin_amdgcn_s_setprio(0);
    asm volatile("s_waitcnt vmcnt(0)" ::: "memory");
    __builtin_amdgcn_s_barrier();
    cur ^= 1;
  }

#pragma unroll
  for (int j = 0; j < 4; j++) {
    const int n = n0 + wc * 64 + j * 16 + ml;
    const float sn = scales[n];
#pragma unroll
    for (int i = 0; i < 4; i++) {
      const int mrow = m0 + wr * 64 + i * 16 + q * 4;
#pragma unroll
      for (int r = 0; r < 4; r++) {
        Cout[(size_t)(mrow + r) * N + n] = (float)acc[i][j][r] * sn * qh[mrow + r];
      }
    }
  }
}

// ---------- launch ----------

extern "C" void kernel_launch(void* const* d_in, const int* in_sizes, int n_in,
                              void* d_out, int out_size, void* d_ws, size_t ws_size,
                              hipStream_t stream) {
  const float* x  = (const float*)d_in[0];  // [4,2048,3072] fp32
  const int*   w1 = (const int*)d_in[1];    // [16384,3072] int32 (int8-valued)
  const float* s1 = (const float*)d_in[2];  // [16384]
  const int*   w2 = (const int*)d_in[3];    // [3072,8192] int32
  const float* s2 = (const float*)d_in[4];  // [3072]
  float* out = (float*)d_out;               // [4,2048,3072] fp32

  signed char* xq  = (signed char*)d_ws;
  float* qs        = (float*)(xq + (size_t)MTOK * HID);
  signed char* w1q = (signed char*)(qs + MTOK);
  signed char* w2q = w1q + (size_t)2 * ITR * HID;
  unsigned short* hid = (unsigned short*)(w2q + (size_t)HID * ITR);
  signed char* hq  = (signed char*)(hid + (size_t)MTOK * ITR);
  float* qh        = (float*)(hq + (size_t)MTOK * ITR);

  quant_x<<<MTOK, 256, 0, stream>>>(x, xq, qs);
  {
    int nw = 2 * ITR * (HID / 4);
    cvt_w1_i8<<<(nw + 255) / 256, 256, 0, stream>>>(w1, w1q);
  }
  {
    int nw = HID * (ITR / 4);
    cvt_w2_i8<<<(nw + 255) / 256, 256, 0, stream>>>(w2, w2q);
  }

  // GEMM1 (int8, 256^2, 2 blocks/CU): hid[8192,8192] bf16
  {
    unsigned nblocks = (2 * ITR / 256) * (MTOK / 256);  // 64*32 = 2048
    gemm1_i8_v3<<<nblocks, 512, 0, stream>>>(xq, w1q, qs, s1, hid);
  }
  quant_h<<<MTOK, 256, 0, stream>>>(hid, hq, qh);
  // GEMM2 (int8, 256x128, 3 blocks/CU): out[8192,3072] fp32
  {
    unsigned nblocks = (HID / 128) * (MTOK / 256);  // 24*32 = 768
    gemm2_i8_v3<<<nblocks, 512, 0, stream>>>(hq, w2q, qh, s2, out);
  }
}

// Round 3
// 1071.640 us; speedup vs baseline: 5.1867x; 5.1867x over previous
//
#include <hip/hip_runtime.h>
#include <cstdint>
#include <cstddef>

// Problem constants (from reference)
constexpr int HID  = 3072;   // hidden size (K of GEMM1, N of GEMM2)
constexpr int ITR  = 8192;   // intermediate size
constexpr int MTOK = 8192;   // B*S = 4*2048 tokens

typedef int i32x4 __attribute__((ext_vector_type(4)));

// ---------- helpers ----------

// RNE fp32 -> bf16 bits
__device__ inline unsigned short f2bf(float f) {
  unsigned int u = __float_as_uint(f);
  u = (u + 0x7FFFu + ((u >> 16) & 1u)) >> 16;
  return (unsigned short)u;
}

// async global->LDS, 16B per lane. LDS dest is wave-uniform base; HW writes
// dest + lane*16.
__device__ inline void gl2lds16(const void* g, void* l) {
  __builtin_amdgcn_global_load_lds(
      (const __attribute__((address_space(1))) unsigned int*)(uintptr_t)g,
      (__attribute__((address_space(3))) unsigned int*)(unsigned int)(uintptr_t)l,
      16, 0, 0);
}

// ---------- prep kernels (unchanged) ----------

__global__ __launch_bounds__(256) void quant_x(
    const float* __restrict__ x, signed char* __restrict__ xq,
    float* __restrict__ qs) {
  const int row = blockIdx.x;
  const int t = threadIdx.x;
  const int wave = t >> 6, lane = t & 63;
  const float4* xr = (const float4*)(x + (size_t)row * HID);  // 768 float4
  float4 v[3];
  float m = 0.f;
#pragma unroll
  for (int k = 0; k < 3; k++) {
    v[k] = xr[t + 256 * k];
    m = fmaxf(m, fmaxf(fmaxf(fabsf(v[k].x), fabsf(v[k].y)),
                       fmaxf(fabsf(v[k].z), fabsf(v[k].w))));
  }
#pragma unroll
  for (int off = 32; off >= 1; off >>= 1) m = fmaxf(m, __shfl_down(m, off));
  __shared__ float wm[4];
  if (lane == 0) wm[wave] = m;
  __syncthreads();
  const float am = fmaxf(fmaxf(wm[0], wm[1]), fmaxf(wm[2], wm[3]));
  const float inv = (am > 1e-30f) ? 127.f / am : 0.f;
  if (t == 0) qs[row] = (am > 1e-30f) ? am / 127.f : 1.f;
  int* out = (int*)(xq + (size_t)row * HID);
#pragma unroll
  for (int k = 0; k < 3; k++) {
    int r0 = __float2int_rn(v[k].x * inv);
    int r1 = __float2int_rn(v[k].y * inv);
    int r2 = __float2int_rn(v[k].z * inv);
    int r3 = __float2int_rn(v[k].w * inv);
    out[t + 256 * k] =
        (r0 & 255) | ((r1 & 255) << 8) | ((r2 & 255) << 16) | ((r3 & 255) << 24);
  }
}

// w1 int32 -> int8 with gate/up 16-row interleave
__global__ __launch_bounds__(256) void cvt_w1_i8(
    const int* __restrict__ in, signed char* __restrict__ out) {
  const int nw = 2 * ITR * (HID / 4);
  int i = blockIdx.x * 256 + threadIdx.x;
  if (i >= nw) return;
  const int R  = i / (HID / 4);
  const int c4 = i % (HID / 4);
  const int q = R >> 5, rm = R & 31;
  const int orig = (rm < 16) ? (q * 16 + rm) : (ITR + q * 16 + (rm - 16));
  int4 w = ((const int4*)(in + (size_t)orig * HID))[c4];
  ((int*)out)[(size_t)R * (HID / 4) + c4] =
      (w.x & 255) | ((w.y & 255) << 8) | ((w.z & 255) << 16) | ((w.w & 255) << 24);
}

// w2 int32 -> int8, layout preserved ([HID, ITR], k contiguous)
__global__ __launch_bounds__(256) void cvt_w2_i8(
    const int* __restrict__ in, signed char* __restrict__ out) {
  const int nw = HID * (ITR / 4);
  int i = blockIdx.x * 256 + threadIdx.x;
  if (i >= nw) return;
  int4 w = ((const int4*)in)[i];
  ((int*)out)[i] =
      (w.x & 255) | ((w.y & 255) << 8) | ((w.z & 255) << 16) | ((w.w & 255) << 24);
}

// per-token int8 quantization of hidden (bf16 in)
__global__ __launch_bounds__(256) void quant_h(
    const unsigned short* __restrict__ h, signed char* __restrict__ hq,
    float* __restrict__ qh) {
  const int row = blockIdx.x;
  const int t = threadIdx.x;
  const int wave = t >> 6, lane = t & 63;
  const uint4* hr = (const uint4*)(h + (size_t)row * ITR);  // 1024 uint4
  uint4 v[4];
  float f[32];
  float m = 0.f;
#pragma unroll
  for (int k = 0; k < 4; k++) {
    v[k] = hr[t + 256 * k];
    const unsigned int w[4] = {v[k].x, v[k].y, v[k].z, v[k].w};
#pragma unroll
    for (int j = 0; j < 4; j++) {
      float lo = __uint_as_float(w[j] << 16);
      float hi = __uint_as_float(w[j] & 0xFFFF0000u);
      f[k * 8 + 2 * j]     = lo;
      f[k * 8 + 2 * j + 1] = hi;
      m = fmaxf(m, fmaxf(fabsf(lo), fabsf(hi)));
    }
  }
#pragma unroll
  for (int off = 32; off >= 1; off >>= 1) m = fmaxf(m, __shfl_down(m, off));
  __shared__ float wm[4];
  if (lane == 0) wm[wave] = m;
  __syncthreads();
  const float am = fmaxf(fmaxf(wm[0], wm[1]), fmaxf(wm[2], wm[3]));
  const float inv = (am > 1e-30f) ? 127.f / am : 0.f;
  if (t == 0) qh[row] = (am > 1e-30f) ? am / 127.f : 1.f;
  int* out = (int*)(hq + (size_t)row * ITR);
#pragma unroll
  for (int k = 0; k < 4; k++) {
#pragma unroll
    for (int j = 0; j < 2; j++) {
      int r0 = __float2int_rn(f[k * 8 + 4 * j]     * inv);
      int r1 = __float2int_rn(f[k * 8 + 4 * j + 1] * inv);
      int r2 = __float2int_rn(f[k * 8 + 4 * j + 2] * inv);
      int r3 = __float2int_rn(f[k * 8 + 4 * j + 3] * inv);
      out[(t + 256 * k) * 2 + j] =
          (r0 & 255) | ((r1 & 255) << 8) | ((r2 & 255) << 16) | ((r3 & 255) << 24);
    }
  }
}

// ---------- GEMM v4: one barrier + one 32-MFMA cluster per K-tile ------------
// Resources identical to v2's proven config: launch_bounds(512,2) (1 block/CU,
// 256-reg budget -- v3's (512,4) forced a 128-reg cap and spilled the 128-reg
// accumulator to scratch: VGPR_Count=64, WRITE_SIZE 10 GB). 3-buffer LDS,
// counted vmcnt(4) (never 0 until the last tile). Per K-tile:
//   vmcnt(4); s_barrier; stage(t+2); 12 frag ds_reads; lgkmcnt(0); 32 MFMA.
// Buffer-overwrite safety: buf (t+2)%3 was last READ at iter t-1; every wave's
// iter-(t-1) reads precede its lgkmcnt(0) -> precede the iter-t barrier ->
// precede any wave's stage(t+2). One barrier per tile is sufficient.

__global__ __launch_bounds__(512, 2) void gemm1_i8_v4(
    const signed char* __restrict__ A, const signed char* __restrict__ B,
    const float* __restrict__ qs, const float* __restrict__ scales,
    unsigned short* __restrict__ Hout) {
  constexpr int K = HID, NT = K / 64;     // 48 K-tiles
  constexpr int MB = MTOK / 256;          // 32
  constexpr int NB = (2 * ITR) / 256;     // 64
  constexpr int PN = 4;

  const int tid = threadIdx.x;
  const int wave = tid >> 6, lane = tid & 63;

  // XCD-bijective swizzle (2048 % 8 == 0) + PN-panel, mb-major inside panel
  const int bid = blockIdx.x;
  const int wg = (bid & 7) * (MB * NB / 8) + (bid >> 3);
  const int panel = wg / (PN * MB);
  const int rem = wg - panel * (PN * MB);
  const int nb = panel * PN + (rem & (PN - 1));
  const int mb = rem / PN;
  const int m0 = mb * 256;
  const int n0 = nb * 256;  // interleaved gate/up column space [0, 2*ITR)

  __shared__ __align__(16) signed char sA[3][256 * 64];  // 48 KB
  __shared__ __align__(16) signed char sB[3][256 * 64];  // 48 KB

  const int srow  = wave * 32 + (lane >> 2);
  const int chunk = (lane & 3) ^ ((lane >> 3) & 3);  // XOR-swizzled src chunk
  const signed char* Ag = A + (size_t)(m0 + srow) * K + chunk * 16;
  const signed char* Bg = B + (size_t)(n0 + srow) * K + chunk * 16;
  const int ldsw = (wave * 32) * 64;  // wave-uniform LDS staging base (bytes)

  auto stage = [&](int ks, int b) {
    gl2lds16(Ag + ks * 64,          &sA[b][ldsw]);
    gl2lds16(Ag + ks * 64 + 16 * K, &sA[b][ldsw + 1024]);
    gl2lds16(Bg + ks * 64,          &sB[b][ldsw]);
    gl2lds16(Bg + ks * 64 + 16 * K, &sB[b][ldsw + 1024]);
  };

  i32x4 acc[8][4];
#pragma unroll
  for (int i = 0; i < 8; i++)
#pragma unroll
    for (int j = 0; j < 4; j++) acc[i][j] = (i32x4){0, 0, 0, 0};

  const int wr = wave >> 2, wc = wave & 3;
  const int ml = lane & 15;
  const int q  = lane >> 4;
  const int slot = (q ^ ((ml >> 1) & 3)) * 16;  // swizzled read slot (bytes)

  // prologue: tiles 0 and 1 in flight (8 outstanding per wave)
  stage(0, 0);
  stage(1, 1);

  int cur = 0, sb = 2;
  for (int t = 0; t < NT; ++t) {
    if (t + 1 < NT) asm volatile("s_waitcnt vmcnt(4)" ::: "memory");
    else            asm volatile("s_waitcnt vmcnt(0)" ::: "memory");
    __builtin_amdgcn_s_barrier();
    if (t + 2 < NT) stage(t + 2, sb);
    const signed char* a_ = sA[cur];
    const signed char* b_ = sB[cur];
    i32x4 av[8], bv[4];
#pragma unroll
    for (int j = 0; j < 4; j++)
      bv[j] = *(const i32x4*)&b_[(wc * 64 + j * 16 + ml) * 64 + slot];
#pragma unroll
    for (int i = 0; i < 8; i++)
      av[i] = *(const i32x4*)&a_[(wr * 128 + i * 16 + ml) * 64 + slot];
    asm volatile("s_waitcnt lgkmcnt(0)" ::: "memory");
    __builtin_amdgcn_sched_barrier(0);
    __builtin_amdgcn_s_setprio(1);
#pragma unroll
    for (int i = 0; i < 8; i++)
#pragma unroll
      for (int j = 0; j < 4; j++)
        acc[i][j] = __builtin_amdgcn_mfma_i32_16x16x64_i8(av[i], bv[j], acc[i][j], 0, 0, 0);
    __builtin_amdgcn_s_setprio(0);
    cur++; if (cur == 3) cur = 0;
    sb++;  if (sb == 3)  sb = 0;
  }

  // Epilogue: j pairs (0,1),(2,3) = (gate,up) for the same 16 hidden cols.
  // C/D layout: col = lane&15, row = (lane>>4)*4 + reg
#pragma unroll
  for (int jp = 0; jp < 2; jp++) {
    const int hcol = (n0 + wc * 64) / 2 + jp * 16 + ml;
    const float sg = scales[hcol];
    const float su = scales[ITR + hcol];
#pragma unroll
    for (int i = 0; i < 8; i++) {
      const int mrow = m0 + wr * 128 + i * 16 + q * 4;
#pragma unroll
      for (int r = 0; r < 4; r++) {
        const float rowqs = qs[mrow + r];
        float g = (float)acc[i][2 * jp][r] * sg * rowqs;
        float u = (float)acc[i][2 * jp + 1][r] * su * rowqs;
        float h = (g / (1.f + __expf(-g))) * u;  // silu(g)*u
        Hout[(size_t)(mrow + r) * ITR + hcol] = f2bf(h);
      }
    }
  }
}

// gemm2: 256x128 tile (768 blocks = 3 exact rounds of 256 CUs), same one-
// barrier schedule, counted vmcnt(3) (3 gl2lds calls per tile per wave).
__global__ __launch_bounds__(512, 2) void gemm2_i8_v4(
    const signed char* __restrict__ A, const signed char* __restrict__ B,
    const float* __restrict__ qh, const float* __restrict__ scales,
    float* __restrict__ Cout) {
  constexpr int K = ITR, N = HID, NT = K / 64;  // 128 K-tiles
  constexpr int MB = MTOK / 256;                // 32
  constexpr int NB = N / 128;                   // 24
  constexpr int PN = 2;

  const int tid = threadIdx.x;
  const int wave = tid >> 6, lane = tid & 63;

  const int bid = blockIdx.x;  // 768 blocks, 768 % 8 == 0
  const int wg = (bid & 7) * (MB * NB / 8) + (bid >> 3);
  const int panel = wg / (PN * MB);
  const int rem = wg - panel * (PN * MB);
  const int nb = panel * PN + (rem & (PN - 1));
  const int mb = rem / PN;
  const int m0 = mb * 256;
  const int n0 = nb * 128;

  __shared__ __align__(16) signed char sA[3][256 * 64];  // 48 KB
  __shared__ __align__(16) signed char sB[3][128 * 64];  // 24 KB

  const int srowA = wave * 32 + (lane >> 2);
  const int srowB = wave * 16 + (lane >> 2);
  const int chunk = (lane & 3) ^ ((lane >> 3) & 3);
  const signed char* Ag = A + (size_t)(m0 + srowA) * K + chunk * 16;
  const signed char* Bg = B + (size_t)(n0 + srowB) * K + chunk * 16;
  const int ldswA = (wave * 32) * 64;
  const int ldswB = (wave * 16) * 64;

  auto stage = [&](int ks, int b) {
    gl2lds16(Ag + ks * 64,          &sA[b][ldswA]);
    gl2lds16(Ag + ks * 64 + 16 * K, &sA[b][ldswA + 1024]);
    gl2lds16(Bg + ks * 64,          &sB[b][ldswB]);
  };

  i32x4 acc[4][4];
#pragma unroll
  for (int i = 0; i < 4; i++)
#pragma unroll
    for (int j = 0; j < 4; j++) acc[i][j] = (i32x4){0, 0, 0, 0};

  const int wr = wave >> 1, wc = wave & 1;  // 4M x 2N, per-wave 64x64
  const int ml = lane & 15;
  const int q  = lane >> 4;
  const int slot = (q ^ ((ml >> 1) & 3)) * 16;

  stage(0, 0);
  stage(1, 1);

  int cur = 0, sb = 2;
  for (int t = 0; t < NT; ++t) {
    if (t + 1 < NT) asm volatile("s_waitcnt vmcnt(3)" ::: "memory");
    else            asm volatile("s_waitcnt vmcnt(0)" ::: "memory");
    __builtin_amdgcn_s_barrier();
    if (t + 2 < NT) stage(t + 2, sb);
    const signed char* a_ = sA[cur];
    const signed char* b_ = sB[cur];
    i32x4 av[4], bv[4];
#pragma unroll
    for (int j = 0; j < 4; j++)
      bv[j] = *(const i32x4*)&b_[(wc * 64 + j * 16 + ml) * 64 + slot];
#pragma unroll
    for (int i = 0; i < 4; i++)
      av[i] = *(const i32x4*)&a_[(wr * 64 + i * 16 + ml) * 64 + slot];
    asm volatile("s_waitcnt lgkmcnt(0)" ::: "memory");
    __builtin_amdgcn_sched_barrier(0);
    __builtin_amdgcn_s_setprio(1);
#pragma unroll
    for (int i = 0; i < 4; i++)
#pragma unroll
      for (int j = 0; j < 4; j++)
        acc[i][j] = __builtin_amdgcn_mfma_i32_16x16x64_i8(av[i], bv[j], acc[i][j], 0, 0, 0);
    __builtin_amdgcn_s_setprio(0);
    cur++; if (cur == 3) cur = 0;
    sb++;  if (sb == 3)  sb = 0;
  }

#pragma unroll
  for (int j = 0; j < 4; j++) {
    const int n = n0 + wc * 64 + j * 16 + ml;
    const float sn = scales[n];
#pragma unroll
    for (int i = 0; i < 4; i++) {
      const int mrow = m0 + wr * 64 + i * 16 + q * 4;
#pragma unroll
      for (int r = 0; r < 4; r++) {
        Cout[(size_t)(mrow + r) * N + n] = (float)acc[i][j][r] * sn * qh[mrow + r];
      }
    }
  }
}

// ---------- launch ----------

extern "C" void kernel_launch(void* const* d_in, const int* in_sizes, int n_in,
                              void* d_out, int out_size, void* d_ws, size_t ws_size,
                              hipStream_t stream) {
  const float* x  = (const float*)d_in[0];  // [4,2048,3072] fp32
  const int*   w1 = (const int*)d_in[1];    // [16384,3072] int32 (int8-valued)
  const float* s1 = (const float*)d_in[2];  // [16384]
  const int*   w2 = (const int*)d_in[3];    // [3072,8192] int32
  const float* s2 = (const float*)d_in[4];  // [3072]
  float* out = (float*)d_out;               // [4,2048,3072] fp32

  signed char* xq  = (signed char*)d_ws;
  float* qs        = (float*)(xq + (size_t)MTOK * HID);
  signed char* w1q = (signed char*)(qs + MTOK);
  signed char* w2q = w1q + (size_t)2 * ITR * HID;
  unsigned short* hid = (unsigned short*)(w2q + (size_t)HID * ITR);
  signed char* hq  = (signed char*)(hid + (size_t)MTOK * ITR);
  float* qh        = (float*)(hq + (size_t)MTOK * ITR);

  quant_x<<<MTOK, 256, 0, stream>>>(x, xq, qs);
  {
    int nw = 2 * ITR * (HID / 4);
    cvt_w1_i8<<<(nw + 255) / 256, 256, 0, stream>>>(w1, w1q);
  }
  {
    int nw = HID * (ITR / 4);
    cvt_w2_i8<<<(nw + 255) / 256, 256, 0, stream>>>(w2, w2q);
  }

  // GEMM1 (int8, 256^2, one-barrier counted-vmcnt): hid[8192,8192] bf16
  {
    unsigned nblocks = (2 * ITR / 256) * (MTOK / 256);  // 64*32 = 2048
    gemm1_i8_v4<<<nblocks, 512, 0, stream>>>(xq, w1q, qs, s1, hid);
  }
  quant_h<<<MTOK, 256, 0, stream>>>(hid, hq, qh);
  // GEMM2 (int8, 256x128, one-barrier counted-vmcnt): out[8192,3072] fp32
  {
    unsigned nblocks = (HID / 128) * (MTOK / 256);  // 24*32 = 768
    gemm2_i8_v4<<<nblocks, 512, 0, stream>>>(hq, w2q, qh, s2, out);
  }
}

// Round 4
// 1054.471 us; speedup vs baseline: 5.2712x; 1.0163x over previous
//
#include <hip/hip_runtime.h>
#include <cstdint>
#include <cstddef>

// Problem constants (from reference)
constexpr int HID  = 3072;   // hidden size (K of GEMM1, N of GEMM2)
constexpr int ITR  = 8192;   // intermediate size
constexpr int MTOK = 8192;   // B*S = 4*2048 tokens

typedef int i32x4 __attribute__((ext_vector_type(4)));

// ---------- helpers ----------

// RNE fp32 -> bf16 bits
__device__ inline unsigned short f2bf(float f) {
  unsigned int u = __float_as_uint(f);
  u = (u + 0x7FFFu + ((u >> 16) & 1u)) >> 16;
  return (unsigned short)u;
}

// async global->LDS, 16B per lane. LDS dest is wave-uniform base; HW writes
// dest + lane*16.
__device__ inline void gl2lds16(const void* g, void* l) {
  __builtin_amdgcn_global_load_lds(
      (const __attribute__((address_space(1))) unsigned int*)(uintptr_t)g,
      (__attribute__((address_space(3))) unsigned int*)(unsigned int)(uintptr_t)l,
      16, 0, 0);
}

// ---------- prep kernels (unchanged) ----------

__global__ __launch_bounds__(256) void quant_x(
    const float* __restrict__ x, signed char* __restrict__ xq,
    float* __restrict__ qs) {
  const int row = blockIdx.x;
  const int t = threadIdx.x;
  const int wave = t >> 6, lane = t & 63;
  const float4* xr = (const float4*)(x + (size_t)row * HID);  // 768 float4
  float4 v[3];
  float m = 0.f;
#pragma unroll
  for (int k = 0; k < 3; k++) {
    v[k] = xr[t + 256 * k];
    m = fmaxf(m, fmaxf(fmaxf(fabsf(v[k].x), fabsf(v[k].y)),
                       fmaxf(fabsf(v[k].z), fabsf(v[k].w))));
  }
#pragma unroll
  for (int off = 32; off >= 1; off >>= 1) m = fmaxf(m, __shfl_down(m, off));
  __shared__ float wm[4];
  if (lane == 0) wm[wave] = m;
  __syncthreads();
  const float am = fmaxf(fmaxf(wm[0], wm[1]), fmaxf(wm[2], wm[3]));
  const float inv = (am > 1e-30f) ? 127.f / am : 0.f;
  if (t == 0) qs[row] = (am > 1e-30f) ? am / 127.f : 1.f;
  int* out = (int*)(xq + (size_t)row * HID);
#pragma unroll
  for (int k = 0; k < 3; k++) {
    int r0 = __float2int_rn(v[k].x * inv);
    int r1 = __float2int_rn(v[k].y * inv);
    int r2 = __float2int_rn(v[k].z * inv);
    int r3 = __float2int_rn(v[k].w * inv);
    out[t + 256 * k] =
        (r0 & 255) | ((r1 & 255) << 8) | ((r2 & 255) << 16) | ((r3 & 255) << 24);
  }
}

// w1 int32 -> int8 with gate/up 16-row interleave
__global__ __launch_bounds__(256) void cvt_w1_i8(
    const int* __restrict__ in, signed char* __restrict__ out) {
  const int nw = 2 * ITR * (HID / 4);
  int i = blockIdx.x * 256 + threadIdx.x;
  if (i >= nw) return;
  const int R  = i / (HID / 4);
  const int c4 = i % (HID / 4);
  const int q = R >> 5, rm = R & 31;
  const int orig = (rm < 16) ? (q * 16 + rm) : (ITR + q * 16 + (rm - 16));
  int4 w = ((const int4*)(in + (size_t)orig * HID))[c4];
  ((int*)out)[(size_t)R * (HID / 4) + c4] =
      (w.x & 255) | ((w.y & 255) << 8) | ((w.z & 255) << 16) | ((w.w & 255) << 24);
}

// w2 int32 -> int8, layout preserved ([HID, ITR], k contiguous)
__global__ __launch_bounds__(256) void cvt_w2_i8(
    const int* __restrict__ in, signed char* __restrict__ out) {
  const int nw = HID * (ITR / 4);
  int i = blockIdx.x * 256 + threadIdx.x;
  if (i >= nw) return;
  int4 w = ((const int4*)in)[i];
  ((int*)out)[i] =
      (w.x & 255) | ((w.y & 255) << 8) | ((w.z & 255) << 16) | ((w.w & 255) << 24);
}

// per-token int8 quantization of hidden (bf16 in)
__global__ __launch_bounds__(256) void quant_h(
    const unsigned short* __restrict__ h, signed char* __restrict__ hq,
    float* __restrict__ qh) {
  const int row = blockIdx.x;
  const int t = threadIdx.x;
  const int wave = t >> 6, lane = t & 63;
  const uint4* hr = (const uint4*)(h + (size_t)row * ITR);  // 1024 uint4
  uint4 v[4];
  float f[32];
  float m = 0.f;
#pragma unroll
  for (int k = 0; k < 4; k++) {
    v[k] = hr[t + 256 * k];
    const unsigned int w[4] = {v[k].x, v[k].y, v[k].z, v[k].w};
#pragma unroll
    for (int j = 0; j < 4; j++) {
      float lo = __uint_as_float(w[j] << 16);
      float hi = __uint_as_float(w[j] & 0xFFFF0000u);
      f[k * 8 + 2 * j]     = lo;
      f[k * 8 + 2 * j + 1] = hi;
      m = fmaxf(m, fmaxf(fabsf(lo), fabsf(hi)));
    }
  }
#pragma unroll
  for (int off = 32; off >= 1; off >>= 1) m = fmaxf(m, __shfl_down(m, off));
  __shared__ float wm[4];
  if (lane == 0) wm[wave] = m;
  __syncthreads();
  const float am = fmaxf(fmaxf(wm[0], wm[1]), fmaxf(wm[2], wm[3]));
  const float inv = (am > 1e-30f) ? 127.f / am : 0.f;
  if (t == 0) qh[row] = (am > 1e-30f) ? am / 127.f : 1.f;
  int* out = (int*)(hq + (size_t)row * ITR);
#pragma unroll
  for (int k = 0; k < 4; k++) {
#pragma unroll
    for (int j = 0; j < 2; j++) {
      int r0 = __float2int_rn(f[k * 8 + 4 * j]     * inv);
      int r1 = __float2int_rn(f[k * 8 + 4 * j + 1] * inv);
      int r2 = __float2int_rn(f[k * 8 + 4 * j + 2] * inv);
      int r3 = __float2int_rn(f[k * 8 + 4 * j + 3] * inv);
      out[(t + 256 * k) * 2 + j] =
          (r0 & 255) | ((r1 & 255) << 8) | ((r2 & 255) << 16) | ((r3 & 255) << 24);
    }
  }
}

// ---------- GEMM v5: v4 structure, UNPINNED ds_read/MFMA overlap -------------
// v4 == v2 in time (417 vs 418 us) proved sync structure is not the limiter.
// Serial-sum model matched measurement to the cycle: per K-tile 2606 cy =
// 1306 (MFMA) + 1129 (96x ds_read_b128 @ 12cy) + 170 (stage/sync). The culprit
// was our explicit lgkmcnt(0)+sched_barrier(0): it forces ALL 12 frag reads to
// complete before ANY MFMA, and barrier-locked waves transition together ->
// CU alternates LDS-only / MFMA-only phases. v5 removes the pins; compiler
// emits fine-grained lgkmcnt(N) (m97 evidence) so a wave's later frag reads
// run under its earlier MFMAs -> wall/tile -> max(1306, ~1390) not the sum.
// Correctness: every read is consumed by an MFMA before the next barrier, so
// compiler waits drain reads before buffer reuse; vmcnt/stage logic unchanged.

__global__ __launch_bounds__(512, 2) void gemm1_i8_v5(
    const signed char* __restrict__ A, const signed char* __restrict__ B,
    const float* __restrict__ qs, const float* __restrict__ scales,
    unsigned short* __restrict__ Hout) {
  constexpr int K = HID, NT = K / 64;     // 48 K-tiles
  constexpr int MB = MTOK / 256;          // 32
  constexpr int NB = (2 * ITR) / 256;     // 64
  constexpr int PN = 4;

  const int tid = threadIdx.x;
  const int wave = tid >> 6, lane = tid & 63;

  // XCD-bijective swizzle (2048 % 8 == 0) + PN-panel, mb-major inside panel
  const int bid = blockIdx.x;
  const int wg = (bid & 7) * (MB * NB / 8) + (bid >> 3);
  const int panel = wg / (PN * MB);
  const int rem = wg - panel * (PN * MB);
  const int nb = panel * PN + (rem & (PN - 1));
  const int mb = rem / PN;
  const int m0 = mb * 256;
  const int n0 = nb * 256;  // interleaved gate/up column space [0, 2*ITR)

  __shared__ __align__(16) signed char sA[3][256 * 64];  // 48 KB
  __shared__ __align__(16) signed char sB[3][256 * 64];  // 48 KB

  const int srow  = wave * 32 + (lane >> 2);
  const int chunk = (lane & 3) ^ ((lane >> 3) & 3);  // XOR-swizzled src chunk
  const signed char* Ag = A + (size_t)(m0 + srow) * K + chunk * 16;
  const signed char* Bg = B + (size_t)(n0 + srow) * K + chunk * 16;
  const int ldsw = (wave * 32) * 64;  // wave-uniform LDS staging base (bytes)

  auto stage = [&](int ks, int b) {
    gl2lds16(Ag + ks * 64,          &sA[b][ldsw]);
    gl2lds16(Ag + ks * 64 + 16 * K, &sA[b][ldsw + 1024]);
    gl2lds16(Bg + ks * 64,          &sB[b][ldsw]);
    gl2lds16(Bg + ks * 64 + 16 * K, &sB[b][ldsw + 1024]);
  };

  i32x4 acc[8][4];
#pragma unroll
  for (int i = 0; i < 8; i++)
#pragma unroll
    for (int j = 0; j < 4; j++) acc[i][j] = (i32x4){0, 0, 0, 0};

  const int wr = wave >> 2, wc = wave & 3;
  const int ml = lane & 15;
  const int q  = lane >> 4;
  const int slot = (q ^ ((ml >> 1) & 3)) * 16;  // swizzled read slot (bytes)

  // prologue: tiles 0 and 1 in flight (8 outstanding per wave)
  stage(0, 0);
  stage(1, 1);

  int cur = 0, sb = 2;
  for (int t = 0; t < NT; ++t) {
    if (t + 1 < NT) asm volatile("s_waitcnt vmcnt(4)" ::: "memory");
    else            asm volatile("s_waitcnt vmcnt(0)" ::: "memory");
    __builtin_amdgcn_s_barrier();
    if (t + 2 < NT) stage(t + 2, sb);
    const signed char* a_ = sA[cur];
    const signed char* b_ = sB[cur];
    i32x4 av[8], bv[4];
#pragma unroll
    for (int j = 0; j < 4; j++)
      bv[j] = *(const i32x4*)&b_[(wc * 64 + j * 16 + ml) * 64 + slot];
#pragma unroll
    for (int i = 0; i < 8; i++)
      av[i] = *(const i32x4*)&a_[(wr * 128 + i * 16 + ml) * 64 + slot];
    // NO lgkmcnt(0)/sched_barrier here: let the compiler emit fine-grained
    // lgkmcnt(N) so frag reads overlap the MFMA stream.
    __builtin_amdgcn_s_setprio(1);
#pragma unroll
    for (int i = 0; i < 8; i++)
#pragma unroll
      for (int j = 0; j < 4; j++)
        acc[i][j] = __builtin_amdgcn_mfma_i32_16x16x64_i8(av[i], bv[j], acc[i][j], 0, 0, 0);
    __builtin_amdgcn_s_setprio(0);
    cur++; if (cur == 3) cur = 0;
    sb++;  if (sb == 3)  sb = 0;
  }

  // Epilogue: j pairs (0,1),(2,3) = (gate,up) for the same 16 hidden cols.
  // C/D layout: col = lane&15, row = (lane>>4)*4 + reg
#pragma unroll
  for (int jp = 0; jp < 2; jp++) {
    const int hcol = (n0 + wc * 64) / 2 + jp * 16 + ml;
    const float sg = scales[hcol];
    const float su = scales[ITR + hcol];
#pragma unroll
    for (int i = 0; i < 8; i++) {
      const int mrow = m0 + wr * 128 + i * 16 + q * 4;
#pragma unroll
      for (int r = 0; r < 4; r++) {
        const float rowqs = qs[mrow + r];
        float g = (float)acc[i][2 * jp][r] * sg * rowqs;
        float u = (float)acc[i][2 * jp + 1][r] * su * rowqs;
        float h = (g / (1.f + __expf(-g))) * u;  // silu(g)*u
        Hout[(size_t)(mrow + r) * ITR + hcol] = f2bf(h);
      }
    }
  }
}

// gemm2: 256x128 tile (768 blocks = 3 exact rounds of 256 CUs), same unpinned
// schedule, counted vmcnt(3) (3 gl2lds calls per tile per wave).
__global__ __launch_bounds__(512, 2) void gemm2_i8_v5(
    const signed char* __restrict__ A, const signed char* __restrict__ B,
    const float* __restrict__ qh, const float* __restrict__ scales,
    float* __restrict__ Cout) {
  constexpr int K = ITR, N = HID, NT = K / 64;  // 128 K-tiles
  constexpr int MB = MTOK / 256;                // 32
  constexpr int NB = N / 128;                   // 24
  constexpr int PN = 2;

  const int tid = threadIdx.x;
  const int wave = tid >> 6, lane = tid & 63;

  const int bid = blockIdx.x;  // 768 blocks, 768 % 8 == 0
  const int wg = (bid & 7) * (MB * NB / 8) + (bid >> 3);
  const int panel = wg / (PN * MB);
  const int rem = wg - panel * (PN * MB);
  const int nb = panel * PN + (rem & (PN - 1));
  const int mb = rem / PN;
  const int m0 = mb * 256;
  const int n0 = nb * 128;

  __shared__ __align__(16) signed char sA[3][256 * 64];  // 48 KB
  __shared__ __align__(16) signed char sB[3][128 * 64];  // 24 KB

  const int srowA = wave * 32 + (lane >> 2);
  const int srowB = wave * 16 + (lane >> 2);
  const int chunk = (lane & 3) ^ ((lane >> 3) & 3);
  const signed char* Ag = A + (size_t)(m0 + srowA) * K + chunk * 16;
  const signed char* Bg = B + (size_t)(n0 + srowB) * K + chunk * 16;
  const int ldswA = (wave * 32) * 64;
  const int ldswB = (wave * 16) * 64;

  auto stage = [&](int ks, int b) {
    gl2lds16(Ag + ks * 64,          &sA[b][ldswA]);
    gl2lds16(Ag + ks * 64 + 16 * K, &sA[b][ldswA + 1024]);
    gl2lds16(Bg + ks * 64,          &sB[b][ldswB]);
  };

  i32x4 acc[4][4];
#pragma unroll
  for (int i = 0; i < 4; i++)
#pragma unroll
    for (int j = 0; j < 4; j++) acc[i][j] = (i32x4){0, 0, 0, 0};

  const int wr = wave >> 1, wc = wave & 1;  // 4M x 2N, per-wave 64x64
  const int ml = lane & 15;
  const int q  = lane >> 4;
  const int slot = (q ^ ((ml >> 1) & 3)) * 16;

  stage(0, 0);
  stage(1, 1);

  int cur = 0, sb = 2;
  for (int t = 0; t < NT; ++t) {
    if (t + 1 < NT) asm volatile("s_waitcnt vmcnt(3)" ::: "memory");
    else            asm volatile("s_waitcnt vmcnt(0)" ::: "memory");
    __builtin_amdgcn_s_barrier();
    if (t + 2 < NT) stage(t + 2, sb);
    const signed char* a_ = sA[cur];
    const signed char* b_ = sB[cur];
    i32x4 av[4], bv[4];
#pragma unroll
    for (int j = 0; j < 4; j++)
      bv[j] = *(const i32x4*)&b_[(wc * 64 + j * 16 + ml) * 64 + slot];
#pragma unroll
    for (int i = 0; i < 4; i++)
      av[i] = *(const i32x4*)&a_[(wr * 64 + i * 16 + ml) * 64 + slot];
    __builtin_amdgcn_s_setprio(1);
#pragma unroll
    for (int i = 0; i < 4; i++)
#pragma unroll
      for (int j = 0; j < 4; j++)
        acc[i][j] = __builtin_amdgcn_mfma_i32_16x16x64_i8(av[i], bv[j], acc[i][j], 0, 0, 0);
    __builtin_amdgcn_s_setprio(0);
    cur++; if (cur == 3) cur = 0;
    sb++;  if (sb == 3)  sb = 0;
  }

#pragma unroll
  for (int j = 0; j < 4; j++) {
    const int n = n0 + wc * 64 + j * 16 + ml;
    const float sn = scales[n];
#pragma unroll
    for (int i = 0; i < 4; i++) {
      const int mrow = m0 + wr * 64 + i * 16 + q * 4;
#pragma unroll
      for (int r = 0; r < 4; r++) {
        Cout[(size_t)(mrow + r) * N + n] = (float)acc[i][j][r] * sn * qh[mrow + r];
      }
    }
  }
}

// ---------- launch ----------

extern "C" void kernel_launch(void* const* d_in, const int* in_sizes, int n_in,
                              void* d_out, int out_size, void* d_ws, size_t ws_size,
                              hipStream_t stream) {
  const float* x  = (const float*)d_in[0];  // [4,2048,3072] fp32
  const int*   w1 = (const int*)d_in[1];    // [16384,3072] int32 (int8-valued)
  const float* s1 = (const float*)d_in[2];  // [16384]
  const int*   w2 = (const int*)d_in[3];    // [3072,8192] int32
  const float* s2 = (const float*)d_in[4];  // [3072]
  float* out = (float*)d_out;               // [4,2048,3072] fp32

  signed char* xq  = (signed char*)d_ws;
  float* qs        = (float*)(xq + (size_t)MTOK * HID);
  signed char* w1q = (signed char*)(qs + MTOK);
  signed char* w2q = w1q + (size_t)2 * ITR * HID;
  unsigned short* hid = (unsigned short*)(w2q + (size_t)HID * ITR);
  signed char* hq  = (signed char*)(hid + (size_t)MTOK * ITR);
  float* qh        = (float*)(hq + (size_t)MTOK * ITR);

  quant_x<<<MTOK, 256, 0, stream>>>(x, xq, qs);
  {
    int nw = 2 * ITR * (HID / 4);
    cvt_w1_i8<<<(nw + 255) / 256, 256, 0, stream>>>(w1, w1q);
  }
  {
    int nw = HID * (ITR / 4);
    cvt_w2_i8<<<(nw + 255) / 256, 256, 0, stream>>>(w2, w2q);
  }

  // GEMM1 (int8, 256^2, unpinned overlap): hid[8192,8192] bf16
  {
    unsigned nblocks = (2 * ITR / 256) * (MTOK / 256);  // 64*32 = 2048
    gemm1_i8_v5<<<nblocks, 512, 0, stream>>>(xq, w1q, qs, s1, hid);
  }
  quant_h<<<MTOK, 256, 0, stream>>>(hid, hq, qh);
  // GEMM2 (int8, 256x128, unpinned overlap): out[8192,3072] fp32
  {
    unsigned nblocks = (HID / 128) * (MTOK / 256);  // 24*32 = 768
    gemm2_i8_v5<<<nblocks, 512, 0, stream>>>(hq, w2q, qh, s2, out);
  }
}